// Round 8
// baseline (525.998 us; speedup 1.0000x reference)
//
#include <hip/hip_runtime.h>

// TemporalAttention N=8192 D=1024, fp32 in/out, fp16-MFMA internals.
// v15 = v14's pipeline (best so far) with MFMA shape 16x16x32 -> 32x32x16:
//   +20% pipe ceiling (2495 vs 2075 TF, m119), half the MFMA instructions,
//   same LDS bytes, same acc budget. Staging/ring/swizzle/barriers are
//   byte-identical to v14 (passed). Only frag addressing + MFMA + epilogue
//   mapping change.
// Operand layouts (derived from verified 16x16x32 mapping + m74/m101 C/D):
//   A/B: lane l -> row/col = l&31, k = (l>>5)*8 + [0..8)  (half8 = 4 VGPR)
//   C/D: col = lane&31, row = (reg&3) + 8*(reg>>2) + 4*(lane>>5), reg 0..15
// Chunk swizzle unchanged: 16B chunk c of row R stored at c^(R&7);
// frag chunk = ks*2 + (lane>>5), R&7 = lane&7 for all frag rows.

using half8    = __attribute__((ext_vector_type(8))) _Float16;
using half4    = __attribute__((ext_vector_type(4))) _Float16;
using floatx16 = __attribute__((ext_vector_type(16))) float;

__device__ __forceinline__ void gload_lds16(const void* g, void* l) {
  __builtin_amdgcn_global_load_lds((const __attribute__((address_space(1))) void*)g,
                                   (__attribute__((address_space(3))) void*)l,
                                   16, 0, 0);
}

template<int N> __device__ __forceinline__ void waitv() {
  if constexpr (N == 8)      asm volatile("s_waitcnt vmcnt(8)" ::: "memory");
  else if constexpr (N == 6) asm volatile("s_waitcnt vmcnt(6)" ::: "memory");
  else                       asm volatile("s_waitcnt vmcnt(0)" ::: "memory");
}

// ---------------- engine S: 256x256, A2+B2, pipelined, 2 barriers/tile ------
// 8 waves 2Mx4N; per-wave 128x64 = A-blocks i:4 x B-blocks j:2 of 32x32.
__device__ __forceinline__ void kloop_s(
    const _Float16* __restrict__ A, const _Float16* __restrict__ B,
    long rowBase, long colBase, int lda, int ldb, int K,
    _Float16* __restrict__ As, _Float16* __restrict__ Bs,
    floatx16 (&acc)[4][2])
{
  const int tid = threadIdx.x;
  const int w = tid >> 6, lane = tid & 63;
  const int l31 = lane & 31, hi = lane >> 5, l7 = lane & 7;
  const int wr = w >> 2, wcn = w & 3;

  // staging identical to v14: pass p covers rows [p*64,p*64+64); source
  // chunk pre-swizzled (chunk c stored at c^(row&7)); LDS dest linear.
  const int sc = ((lane & 7) ^ (lane >> 3)) << 3;
  const _Float16* Agp[4]; const _Float16* Bgp[4];
#pragma unroll
  for (int p = 0; p < 4; ++p) {
    Agp[p] = A + (rowBase + p * 64 + (tid >> 3)) * (long)lda + sc;
    Bgp[p] = B + (colBase + p * 64 + (tid >> 3)) * (long)ldb + sc;
  }
  const int ldsOff = tid * 8;

  const int aRow = wr * 128 + l31;            // +32*i
  const int bRow = wcn * 64 + l31;            // +32*j
  int pcs[4];
#pragma unroll
  for (int ks = 0; ks < 4; ++ks) pcs[ks] = (((ks << 1) | hi) ^ l7) << 3;

  auto stageA = [&](int t) {
    _Float16* dst = As + (t & 1) * 16384;
    const int ko = t << 6;
#pragma unroll
    for (int p = 0; p < 4; ++p) gload_lds16(Agp[p] + ko, dst + p * 4096 + ldsOff);
  };
  auto stageB = [&](int t) {
    _Float16* dst = Bs + (t & 1) * 16384;
    const int ko = t << 6;
#pragma unroll
    for (int p = 0; p < 4; ++p) gload_lds16(Bgp[p] + ko, dst + p * 4096 + ldsOff);
  };

  const int NT = K >> 6;
  stageA(0); stageB(0); stageA(1); stageB(1);
  waitv<8>(); __builtin_amdgcn_s_barrier();   // tile 0 published; t1 in flight

  for (int t = 0; t < NT; ++t) {
    const _Float16* Asl = As + (t & 1) * 16384;
    const _Float16* Bsl = Bs + (t & 1) * 16384;
    half8 a[4][4], b[2][4];

#define RD_G(ks)                                                             \
    _Pragma("unroll")                                                        \
    for (int j = 0; j < 2; ++j)                                              \
      b[j][ks] = *(const half8*)&Bsl[(bRow + 32 * j) * 64 + pcs[ks]];        \
    _Pragma("unroll")                                                        \
    for (int i = 0; i < 4; ++i)                                              \
      a[i][ks] = *(const half8*)&Asl[(aRow + 32 * i) * 64 + pcs[ks]];
#define MM_G(ks)                                                             \
    _Pragma("unroll")                                                        \
    for (int i = 0; i < 4; ++i)                                              \
      _Pragma("unroll")                                                      \
      for (int j = 0; j < 2; ++j)                                            \
        acc[i][j] = __builtin_amdgcn_mfma_f32_32x32x16_f16(                  \
            a[i][ks], b[j][ks], acc[i][j], 0, 0, 0);

    // reads lead MFMA by one group; no fences between -> overlap (v14).
    RD_G(0) RD_G(1)
    MM_G(0)
    RD_G(2)
    MM_G(1)
    RD_G(3)
    MM_G(2)
    // M: all LDS reads of tile t retired CU-wide; slot (t&1) now free.
    asm volatile("s_waitcnt lgkmcnt(0)" ::: "memory");
    __builtin_amdgcn_s_barrier();
    if (t + 2 < NT) { stageA(t + 2); stageB(t + 2); }
    MM_G(3)
    if (t < NT - 1) {
      if (t + 2 < NT) waitv<8>(); else waitv<0>();  // publish t+1; t+2 in flight
      __builtin_amdgcn_s_barrier();
    }
#undef RD_G
#undef MM_G
  }
}

// ---------------- engine V: 256x128, A3+B3, pipelined, 1 barrier/tile -------
// 8 waves 4Mx2N; per-wave 64x64 = 2x2 blocks of 32x32.
__device__ __forceinline__ void kloop_v(
    const _Float16* __restrict__ A, const _Float16* __restrict__ B,
    long rowBase, long colBase, int lda, int ldb, int K,
    _Float16* __restrict__ As, _Float16* __restrict__ Bs,
    floatx16 (&acc)[2][2])
{
  const int tid = threadIdx.x;
  const int w = tid >> 6, lane = tid & 63;
  const int l31 = lane & 31, hi = lane >> 5, l7 = lane & 7;
  const int wr = w >> 1, wcn = w & 1;

  const int sc = ((lane & 7) ^ (lane >> 3)) << 3;
  const _Float16* Agp[4]; const _Float16* Bgp[2];
#pragma unroll
  for (int p = 0; p < 4; ++p)
    Agp[p] = A + (rowBase + p * 64 + (tid >> 3)) * (long)lda + sc;
#pragma unroll
  for (int p = 0; p < 2; ++p)
    Bgp[p] = B + (colBase + p * 64 + (tid >> 3)) * (long)ldb + sc;
  const int ldsOff = tid * 8;

  const int aRow = wr * 64 + l31;             // +32*i
  const int bRow = wcn * 64 + l31;            // +32*j
  int pcs[4];
#pragma unroll
  for (int ks = 0; ks < 4; ++ks) pcs[ks] = (((ks << 1) | hi) ^ l7) << 3;

  auto stage = [&](int t) {                    // 6 gloads; slot (t%3)
    const int s = t % 3;
    _Float16* dA = As + s * 16384;
    _Float16* dB = Bs + s * 8192;
    const int ko = t << 6;
#pragma unroll
    for (int p = 0; p < 4; ++p) gload_lds16(Agp[p] + ko, dA + p * 4096 + ldsOff);
#pragma unroll
    for (int p = 0; p < 2; ++p) gload_lds16(Bgp[p] + ko, dB + p * 4096 + ldsOff);
  };

  const int NT = K >> 6;
  stage(0); stage(1);
  waitv<6>(); __builtin_amdgcn_s_barrier();    // tile 0 published; t1 in flight

  for (int t = 0; t < NT; ++t) {
    const int s = t % 3;
    const _Float16* Asl = As + s * 16384;
    const _Float16* Bsl = Bs + s * 8192;
    half8 a[2][4], b[2][4];
#pragma unroll
    for (int ks = 0; ks < 4; ++ks) {
#pragma unroll
      for (int j = 0; j < 2; ++j)
        b[j][ks] = *(const half8*)&Bsl[(bRow + 32 * j) * 64 + pcs[ks]];
#pragma unroll
      for (int i = 0; i < 2; ++i)
        a[i][ks] = *(const half8*)&Asl[(aRow + 32 * i) * 64 + pcs[ks]];
    }
#pragma unroll
    for (int ks = 0; ks < 2; ++ks)
#pragma unroll
      for (int i = 0; i < 2; ++i)
#pragma unroll
        for (int j = 0; j < 2; ++j)
          acc[i][j] = __builtin_amdgcn_mfma_f32_32x32x16_f16(a[i][ks], b[j][ks], acc[i][j], 0, 0, 0);
    if (t + 2 < NT) stage(t + 2);              // slot (t+2)%3: retired at t-1
#pragma unroll
    for (int ks = 2; ks < 4; ++ks)
#pragma unroll
      for (int i = 0; i < 2; ++i)
#pragma unroll
        for (int j = 0; j < 2; ++j)
          acc[i][j] = __builtin_amdgcn_mfma_f32_32x32x16_f16(a[i][ks], b[j][ks], acc[i][j], 0, 0, 0);
    if (t < NT - 1) {
      if (t + 2 < NT) waitv<6>(); else waitv<0>();
      __builtin_amdgcn_s_barrier();            // publish t+1
    }
  }
}

// ---------------- kernels ---------------------------------------------------
// BIAS_MODE: 0 none, 1 add per-col, 2 add per-row, 3 MUL per-row (invL).
// OUT_MODE: 0 fp16, 2 fp32.
template<int BIAS_MODE, int OUT_MODE>
__global__ __launch_bounds__(512, 2)
void gemmS_k(const _Float16* __restrict__ A, const _Float16* __restrict__ B,
             void* __restrict__ Cout, const float* __restrict__ bias,
             int lda, int ldb, int ldc, int K, float outScale)
{
  __shared__ __align__(16) _Float16 As[2 * 16384];
  __shared__ __align__(16) _Float16 Bs[2 * 16384];
  const long rowBase = (long)blockIdx.y * 256;
  const long colBase = (long)blockIdx.x * 256;

  floatx16 acc[4][2] = {};
  kloop_s(A, B, rowBase, colBase, lda, ldb, K, As, Bs, acc);

  const int tid = threadIdx.x;
  const int w = tid >> 6, lane = tid & 63;
  const int l31 = lane & 31, hi = lane >> 5;
  const int wr = w >> 2, wcn = w & 3;
#pragma unroll
  for (int i = 0; i < 4; ++i) {
#pragma unroll
    for (int reg = 0; reg < 16; ++reg) {
      const long rowg = rowBase + wr * 128 + 32 * i + (reg & 3) + 8 * (reg >> 2) + 4 * hi;
#pragma unroll
      for (int j = 0; j < 2; ++j) {
        const long colg = colBase + wcn * 64 + 32 * j + l31;
        float v = acc[i][j][reg];
        if (BIAS_MODE == 1) v += bias[colg];
        if (BIAS_MODE == 2) v += bias[rowg];
        v *= outScale;
        if (OUT_MODE == 2) ((float*)Cout)[rowg * ldc + colg] = v;
        else               ((_Float16*)Cout)[rowg * ldc + colg] = (_Float16)v;
      }
    }
  }
}

template<int BIAS_MODE, int OUT_MODE, int SWZ>
__global__ __launch_bounds__(512, 2)
void gemmV_k(const _Float16* __restrict__ A, const _Float16* __restrict__ B,
             void* __restrict__ Cout, const float* __restrict__ bias,
             int lda, int ldb, int ldc, int K, float outScale)
{
  __shared__ __align__(16) _Float16 As[3 * 16384];
  __shared__ __align__(16) _Float16 Bs[3 * 8192];

  int tx, ty;
  if (SWZ) {
    const int bflat = blockIdx.y * gridDim.x + blockIdx.x;  // dispatch-linear
    ty = bflat % gridDim.y;
    tx = bflat / gridDim.y;
  } else {
    tx = blockIdx.x; ty = blockIdx.y;
  }
  const long rowBase = (long)ty * 256;
  const long colBase = (long)tx * 128;

  floatx16 acc[2][2] = {};
  kloop_v(A, B, rowBase, colBase, lda, ldb, K, As, Bs, acc);

  const int tid = threadIdx.x;
  const int w = tid >> 6, lane = tid & 63;
  const int l31 = lane & 31, hi = lane >> 5;
  const int wr = w >> 1, wcn = w & 1;
#pragma unroll
  for (int i = 0; i < 2; ++i) {
#pragma unroll
    for (int reg = 0; reg < 16; ++reg) {
      const long rowg = rowBase + wr * 64 + 32 * i + (reg & 3) + 8 * (reg >> 2) + 4 * hi;
#pragma unroll
      for (int j = 0; j < 2; ++j) {
        const long colg = colBase + wcn * 64 + 32 * j + l31;
        float v = acc[i][j][reg];
        if (BIAS_MODE == 1) v += bias[colg];
        if (BIAS_MODE == 2) v += bias[rowg];
        if (BIAS_MODE == 3) v *= bias[rowg];
        v *= outScale;
        if (OUT_MODE == 2) ((float*)Cout)[rowg * ldc + colg] = v;
        else               ((_Float16*)Cout)[rowg * ldc + colg] = (_Float16)v;
      }
    }
  }
}

// U = exp(qkScale*(Q*K^T) + decay_bias - 4), fp16; per-(row,col-tile) sums.
// Engine S + fused exp epilogue; sL scratch aliased into As.
__global__ __launch_bounds__(512, 2)
void gemm_statsS_k(const _Float16* __restrict__ A, const _Float16* __restrict__ B,
                   const float* __restrict__ ts, _Float16* __restrict__ U,
                   float* __restrict__ part, int lda, int ldb, int N, int K,
                   float qkScale)
{
  __shared__ __align__(16) _Float16 As[2 * 16384];
  __shared__ __align__(16) _Float16 Bs[2 * 16384];
  const int tid = threadIdx.x;
  const long rowBase = (long)blockIdx.y * 256;
  const long colBase = (long)blockIdx.x * 256;

  floatx16 acc[4][2] = {};
  kloop_s(A, B, rowBase, colBase, lda, ldb, K, As, Bs, acc);

  const int w = tid >> 6, lane = tid & 63;
  const int l31 = lane & 31, hi = lane >> 5;
  const int wr = w >> 2, wcn = w & 3;
  const float inv_td = 1.0f / 86400.0f;

  float tc[2];
#pragma unroll
  for (int j = 0; j < 2; ++j) tc[j] = ts[colBase + wcn * 64 + 32 * j + l31];

  float* sl = (float*)As;
  __syncthreads();
  // u = exp(s - 4); s = qk/32 + log-decay ~ qk/32 - |dt|/TD (exact to 2.2e-6).
#pragma unroll
  for (int i = 0; i < 4; ++i) {
#pragma unroll
    for (int reg = 0; reg < 16; ++reg) {
      const int rowl = wr * 128 + 32 * i + (reg & 3) + 8 * (reg >> 2) + 4 * hi;
      const float tr = ts[rowBase + rowl];
      float ls = 0.0f;
#pragma unroll
      for (int j = 0; j < 2; ++j) {
        const int coll = wcn * 64 + 32 * j + l31;
        const float sv = acc[i][j][reg] * qkScale
                       - fabsf(tr - tc[j]) * inv_td - 4.0f;
        const float u = __expf(sv);
        ls += u;
        U[(rowBase + rowl) * (long)N + (colBase + coll)] = (_Float16)u;
      }
      // row-sum over the wave's 64-col band: lanes 0-31 hold this row's cols
      // (lanes 32-63 hold row+4) -> reduce within each 32-lane half.
      for (int mask = 1; mask <= 16; mask <<= 1)
        ls += __shfl_xor(ls, mask, 64);
      if (l31 == 0) sl[(wr * 4 + wcn) * 128 + 32 * i + (reg & 3) + 8 * (reg >> 2) + 4 * hi] = ls;
    }
  }
  __syncthreads();
  if (tid < 256) {
    const int band = tid & 127, hib = tid >> 7;
    part[(rowBase + tid) * 32 + blockIdx.x] =
        sl[(hib * 4 + 0) * 128 + band] + sl[(hib * 4 + 1) * 128 + band] +
        sl[(hib * 4 + 2) * 128 + band] + sl[(hib * 4 + 3) * 128 + band];
  }
}

__global__ void combine_k(const float* __restrict__ part, float* __restrict__ invL) {
  const int r = blockIdx.x * 256 + threadIdx.x;
  float L = 0.0f;
  for (int c = 0; c < 32; ++c) L += part[(long)r * 32 + c];
  invL[r] = 1.0f / L;
}

// fp32 -> fp16, 4/thread
__global__ void cvt_k(const float* __restrict__ in, _Float16* __restrict__ out, int n) {
  const int i = (blockIdx.x * 256 + threadIdx.x) * 4;
  if (i >= n) return;
  const float4 v = *(const float4*)(in + i);
  half4 o = { (_Float16)v.x, (_Float16)v.y, (_Float16)v.z, (_Float16)v.w };
  *(half4*)(out + i) = o;
}

extern "C" void kernel_launch(void* const* d_in, const int* in_sizes, int n_in,
                              void* d_out, int out_size, void* d_ws, size_t ws_size,
                              hipStream_t stream)
{
  (void)in_sizes; (void)n_in; (void)out_size; (void)ws_size;
  const int N = 8192, D = 1024;
  const float* x  = (const float*)d_in[0];
  const float* ts = (const float*)d_in[1];
  const float* Wq = (const float*)d_in[2];
  const float* bq = (const float*)d_in[3];
  const float* Wk = (const float*)d_in[4];
  const float* bk = (const float*)d_in[5];
  const float* Wv = (const float*)d_in[6];
  const float* bv = (const float*)d_in[7];

  char* p = (char*)d_ws;
  auto grab = [&](size_t bytes) {
    char* r = p;
    p += (bytes + 255) & ~(size_t)255;
    return r;
  };
  _Float16* xh    = (_Float16*)grab((size_t)N * D * 2);
  _Float16* wqkh  = (_Float16*)grab((size_t)2 * D * D * 2); // Wq rows then Wk rows
  _Float16* wvh   = (_Float16*)grab((size_t)D * D * 2);
  _Float16* QKcat = (_Float16*)grab((size_t)N * 2 * D * 2); // [N x 2D], Q | K
  _Float16* VTh   = (_Float16*)grab((size_t)D * N * 2);     // V^T [D x N]
  _Float16* Uh    = (_Float16*)grab((size_t)N * N * 2);     // U = exp(S - 4)
  float*    part  = (float*)grab((size_t)N * 32 * sizeof(float));
  float*    invL  = (float*)grab((size_t)N * sizeof(float));
  float*    bcat  = (float*)grab((size_t)2 * D * sizeof(float));

  cvt_k<<<N * D / 1024, 256, 0, stream>>>(x,  xh,  N * D);
  cvt_k<<<D * D / 1024, 256, 0, stream>>>(Wq, wqkh,         D * D);
  cvt_k<<<D * D / 1024, 256, 0, stream>>>(Wk, wqkh + D * D, D * D);
  cvt_k<<<D * D / 1024, 256, 0, stream>>>(Wv, wvh, D * D);
  hipMemcpyAsync(bcat,     bq, D * sizeof(float), hipMemcpyDeviceToDevice, stream);
  hipMemcpyAsync(bcat + D, bk, D * sizeof(float), hipMemcpyDeviceToDevice, stream);

  dim3 blk(512);
  // [Q | K] = x [Wq;Wk]^T + [bq|bk]; engine S -> grid (8,32)=256 wg.
  gemmS_k<1, 0><<<dim3(2 * D / 256, N / 256), blk, 0, stream>>>(
      xh, wqkh, QKcat, bcat, D, D, 2 * D, D, 1.0f);
  // V^T = Wv x^T + bv; engine V -> grid (64,4)=256 wg.
  gemmV_k<2, 0, 0><<<dim3(N / 128, D / 256), blk, 0, stream>>>(
      wvh, xh, VTh, bv, D, D, N, D, 1.0f);
  // U = exp(QK^T/32 + decay - 4) + partial row sums; engine S, (32,32)=1024 wg.
  gemm_statsS_k<<<dim3(N / 256, N / 256), blk, 0, stream>>>(
      QKcat, QKcat + D, ts, Uh, part, 2 * D, 2 * D, N, D, 1.0f / 32.0f);
  combine_k<<<N / 256, 256, 0, stream>>>(part, invL);
  // O = (U V) * invL; engine V -> grid (8,32)=256 wg, XCD swz.
  gemmV_k<3, 2, 1><<<dim3(D / 128, N / 256), blk, 0, stream>>>(
      Uh, VTh, d_out, invL, N, N, D, N, 1.0f);
}